// Round 1
// baseline (751.994 us; speedup 1.0000x reference)
//
#include <hip/hip_runtime.h>

#define BB 4096
#define CC 32000
#define NCHUNK 16
#define ROWS_PER_CHUNK (BB / NCHUNK)  // 256

// ---------------- Kernel A: rcpZ[b] = 1 / sum_c exp(x[b,c]) ----------------
// One block (256 threads) per row; float4 loads; wave+LDS reduction.
__global__ __launch_bounds__(256) void row_sumexp(const float* __restrict__ x,
                                                  float* __restrict__ rcpZ) {
    const int row = blockIdx.x;
    const int t = threadIdx.x;
    const float4* rp4 = (const float4*)(x + (size_t)row * CC);
    float s = 0.f;
    for (int i = t; i < CC / 4; i += 256) {
        float4 v = rp4[i];
        s += __expf(v.x) + __expf(v.y) + __expf(v.z) + __expf(v.w);
    }
    // wave (64-lane) reduce
    for (int off = 32; off > 0; off >>= 1) s += __shfl_down(s, off);
    __shared__ float wsum[4];
    if ((t & 63) == 0) wsum[t >> 6] = s;
    __syncthreads();
    if (t == 0) {
        float tot = wsum[0] + wsum[1] + wsum[2] + wsum[3];
        rcpZ[row] = 1.0f / tot;
    }
}

// ------------- Kernel B: partial[chunk][c] = sum_{b in chunk} exp(x[b,c])*rcpZ[b]
// grid.x = CC/256 column tiles, grid.y = NCHUNK row chunks. Thread owns one column.
// At each row iteration the block reads 256 contiguous floats (coalesced).
__global__ __launch_bounds__(256) void col_partial(const float* __restrict__ x,
                                                   const float* __restrict__ rcpZ,
                                                   float* __restrict__ partial) {
    const int c = blockIdx.x * 256 + threadIdx.x;  // < 32000 exactly
    const int b0 = blockIdx.y * ROWS_PER_CHUNK;
    __shared__ float rz[ROWS_PER_CHUNK];
    for (int i = threadIdx.x; i < ROWS_PER_CHUNK; i += 256) rz[i] = rcpZ[b0 + i];
    __syncthreads();
    const float* p = x + (size_t)b0 * CC + c;
    float acc = 0.f;
#pragma unroll 4
    for (int i = 0; i < ROWS_PER_CHUNK; ++i) {
        acc += __expf(p[(size_t)i * CC]) * rz[i];
    }
    partial[(size_t)blockIdx.y * CC + c] = acc;
}

// ---------------- bincount: counts[target[i]] += 1 ----------------
__global__ void bincount_k(const int* __restrict__ tgt, float* __restrict__ counts) {
    int i = blockIdx.x * 256 + threadIdx.x;
    if (i < BB) atomicAdd(&counts[tgt[i]], 1.0f);
}

// ---------------- finalize: loss = mean_c |sum_partial[c] - counts[c]| / B ----
__global__ __launch_bounds__(256) void finalize(const float* __restrict__ partial,
                                                const float* __restrict__ counts,
                                                float* __restrict__ out) {
    const int c = blockIdx.x * 256 + threadIdx.x;  // < 32000 exactly
    float s = 0.f;
#pragma unroll
    for (int k = 0; k < NCHUNK; ++k) s += partial[(size_t)k * CC + c];
    float v = fabsf(s - counts[c]) * (1.0f / BB);
    for (int off = 32; off > 0; off >>= 1) v += __shfl_down(v, off);
    __shared__ float wsum[4];
    const int t = threadIdx.x;
    if ((t & 63) == 0) wsum[t >> 6] = v;
    __syncthreads();
    if (t == 0) {
        float tot = (wsum[0] + wsum[1] + wsum[2] + wsum[3]) * (1.0f / CC);
        atomicAdd(out, tot);
    }
}

extern "C" void kernel_launch(void* const* d_in, const int* in_sizes, int n_in,
                              void* d_out, int out_size, void* d_ws, size_t ws_size,
                              hipStream_t stream) {
    const float* x = (const float*)d_in[0];
    const int* tgt = (const int*)d_in[1];
    float* out = (float*)d_out;

    // workspace layout (floats): counts[CC] | rcpZ[BB] | partial[NCHUNK*CC]
    float* counts = (float*)d_ws;
    float* rcpZ = counts + CC;
    float* partial = rcpZ + BB;

    hipMemsetAsync(counts, 0, CC * sizeof(float), stream);
    hipMemsetAsync(d_out, 0, sizeof(float), stream);

    bincount_k<<<(BB + 255) / 256, 256, 0, stream>>>(tgt, counts);
    row_sumexp<<<BB, 256, 0, stream>>>(x, rcpZ);
    col_partial<<<dim3(CC / 256, NCHUNK), 256, 0, stream>>>(x, rcpZ, partial);
    finalize<<<CC / 256, 256, 0, stream>>>(partial, counts, out);
}

// Round 3
// 712.286 us; speedup vs baseline: 1.0557x; 1.0557x over previous
//
#include <hip/hip_runtime.h>

#define BB 4096
#define CC 32000
#define W32 8000            // uint32 words per row (4 fp8 cols each)
#define W64 4000            // uint2 words per row (8 fp8 cols each)
#define NCHUNK 64
#define RPC (BB / NCHUNK)   // 64 rows per chunk
#define FBLK 125            // finalize blocks (125*256 == 32000)

typedef float v2f __attribute__((ext_vector_type(2)));
typedef float v4f __attribute__((ext_vector_type(4)));

#if defined(__has_builtin)
#if __has_builtin(__builtin_amdgcn_cvt_pk_fp8_f32) && __has_builtin(__builtin_amdgcn_cvt_pk_f32_fp8)
#define HW_FP8 1
#endif
#endif

#ifndef HW_FP8
// software e4m3fn encode/decode (positive values only; v pre-clamped <= 440)
__device__ inline unsigned sw_enc(float v) {
    if (v < 0.015625f) return (unsigned)__float2int_rn(v * 512.0f);  // subnormal, ulp 2^-9
    unsigned u = __float_as_uint(v);
    unsigned m = (u >> 20) & 7;
    unsigned rest = u & 0xfffff;
    int e32 = (int)((u >> 23) & 0xff);
    if (rest > 0x80000 || (rest == 0x80000 && (m & 1))) { if (++m == 8) { m = 0; e32++; } }
    int ee = e32 - 127 + 7;
    if (ee > 15) { ee = 15; m = 6; }   // clamp to 448
    return ((unsigned)ee << 3) | m;
}
__device__ inline float sw_dec(unsigned b) {
    unsigned e = (b >> 3) & 0xf, m = b & 7;
    if (e == 0) return (float)m * 0.001953125f;
    return __uint_as_float(((e - 7 + 127) << 23) | (m << 20));
}
#endif

// ---- Pass A: read x once (nontemporal), Z per row, stash fp8(exp(x)), fused bincount
__global__ __launch_bounds__(256) void row_pass(const float* __restrict__ x,
                                                const int* __restrict__ tgt,
                                                unsigned* __restrict__ stash,
                                                float* __restrict__ rcpZ,
                                                float* __restrict__ counts) {
    const int row = blockIdx.x;
    const int t = threadIdx.x;
    const v4f* rp4 = (const v4f*)(x + (size_t)row * CC);
    unsigned* sp = stash + (size_t)row * W32;
    float s = 0.f;
    for (int i = t; i < W32; i += 256) {
        v4f v = __builtin_nontemporal_load(&rp4[i]);
        float e0 = __expf(v.x), e1 = __expf(v.y), e2 = __expf(v.z), e3 = __expf(v.w);
        s += e0 + e1 + e2 + e3;
#ifdef HW_FP8
        int w = __builtin_amdgcn_cvt_pk_fp8_f32(fminf(e0, 440.f), fminf(e1, 440.f), 0, false);
        w = __builtin_amdgcn_cvt_pk_fp8_f32(fminf(e2, 440.f), fminf(e3, 440.f), w, true);
        sp[i] = (unsigned)w;
#else
        sp[i] = sw_enc(fminf(e0, 440.f)) | (sw_enc(fminf(e1, 440.f)) << 8) |
                (sw_enc(fminf(e2, 440.f)) << 16) | (sw_enc(fminf(e3, 440.f)) << 24);
#endif
    }
    for (int off = 32; off > 0; off >>= 1) s += __shfl_down(s, off);
    __shared__ float wsum[4];
    if ((t & 63) == 0) wsum[t >> 6] = s;
    __syncthreads();
    if (t == 0) {
        rcpZ[row] = 1.0f / (wsum[0] + wsum[1] + wsum[2] + wsum[3]);
        atomicAdd(&counts[tgt[row]], 1.0f);   // fused bincount: one atomic per row
    }
}

// ---- Pass B: column partials from the (LLC-resident) fp8 stash
__global__ __launch_bounds__(256) void col_pass(const uint2* __restrict__ stash,
                                                const float* __restrict__ rcpZ,
                                                float* __restrict__ partial) {
    const int g = blockIdx.x * 256 + threadIdx.x;  // uint2 index within row
    const int b0 = blockIdx.y * RPC;
    __shared__ float rz[RPC];
    if (threadIdx.x < RPC) rz[threadIdx.x] = rcpZ[b0 + threadIdx.x];
    __syncthreads();
    if (g >= W64) return;
    float a0 = 0, a1 = 0, a2 = 0, a3 = 0, a4 = 0, a5 = 0, a6 = 0, a7 = 0;
    const uint2* p = stash + (size_t)b0 * W64 + g;
#pragma unroll 4
    for (int i = 0; i < RPC; ++i) {
        uint2 w = p[(size_t)i * W64];
        float r = rz[i];
#ifdef HW_FP8
        v2f f01 = __builtin_amdgcn_cvt_pk_f32_fp8((int)w.x, false);
        v2f f23 = __builtin_amdgcn_cvt_pk_f32_fp8((int)w.x, true);
        v2f f45 = __builtin_amdgcn_cvt_pk_f32_fp8((int)w.y, false);
        v2f f67 = __builtin_amdgcn_cvt_pk_f32_fp8((int)w.y, true);
        a0 += f01.x * r; a1 += f01.y * r; a2 += f23.x * r; a3 += f23.y * r;
        a4 += f45.x * r; a5 += f45.y * r; a6 += f67.x * r; a7 += f67.y * r;
#else
        a0 += sw_dec(w.x & 0xff) * r;         a1 += sw_dec((w.x >> 8) & 0xff) * r;
        a2 += sw_dec((w.x >> 16) & 0xff) * r; a3 += sw_dec(w.x >> 24) * r;
        a4 += sw_dec(w.y & 0xff) * r;         a5 += sw_dec((w.y >> 8) & 0xff) * r;
        a6 += sw_dec((w.y >> 16) & 0xff) * r; a7 += sw_dec(w.y >> 24) * r;
#endif
    }
    float* d = partial + (size_t)blockIdx.y * CC + (size_t)g * 8;
    float4 o0 = {a0, a1, a2, a3}, o1 = {a4, a5, a6, a7};
    ((float4*)d)[0] = o0;
    ((float4*)d)[1] = o1;
}

// ---- Finalize: loss = (1/(B*C)) * sum_c |S_c - counts_c|; last block writes out
__global__ __launch_bounds__(256) void finalize(const float* __restrict__ partial,
                                                const float* __restrict__ counts,
                                                float* __restrict__ total,
                                                unsigned* __restrict__ blkcnt,
                                                float* __restrict__ out) {
    const int c = blockIdx.x * 256 + threadIdx.x;  // < 32000 exactly
    float s = 0.f;
#pragma unroll
    for (int k = 0; k < NCHUNK; ++k) s += partial[(size_t)k * CC + c];
    float v = fabsf(s - counts[c]);
    for (int off = 32; off > 0; off >>= 1) v += __shfl_down(v, off);
    __shared__ float wsum[4];
    if ((threadIdx.x & 63) == 0) wsum[threadIdx.x >> 6] = v;
    __syncthreads();
    if (threadIdx.x == 0) {
        atomicAdd(total, wsum[0] + wsum[1] + wsum[2] + wsum[3]);
        __threadfence();
        unsigned prev = atomicAdd(blkcnt, 1u);
        if (prev == FBLK - 1) {
            float tot = atomicAdd(total, 0.0f);  // device-scope read of final value
            out[0] = tot * (1.0f / ((float)BB * (float)CC));
        }
    }
}

extern "C" void kernel_launch(void* const* d_in, const int* in_sizes, int n_in,
                              void* d_out, int out_size, void* d_ws, size_t ws_size,
                              hipStream_t stream) {
    const float* x = (const float*)d_in[0];
    const int* tgt = (const int*)d_in[1];
    float* out = (float*)d_out;

    // ws layout: stash[BB*W32 u32] | partial[NCHUNK*CC f32] | counts[CC f32] | total f32 | blkcnt u32 | rcpZ[BB f32]
    char* base = (char*)d_ws;
    unsigned* stash = (unsigned*)base;                                   // 131,072,000 B
    float* partial = (float*)(base + (size_t)BB * W32 * 4);              // 8,192,000 B
    float* counts = (float*)(base + (size_t)BB * W32 * 4 + (size_t)NCHUNK * CC * 4);
    float* total = counts + CC;
    unsigned* blkcnt = (unsigned*)(total + 1);
    float* rcpZ = (float*)(blkcnt + 1);

    // zero counts + total + blkcnt in one memset (128,008 B)
    (void)hipMemsetAsync(counts, 0, (size_t)(CC + 2) * 4, stream);

    row_pass<<<BB, 256, 0, stream>>>(x, tgt, stash, rcpZ, counts);
    col_pass<<<dim3((W64 + 255) / 256, NCHUNK), 256, 0, stream>>>((const uint2*)stash, rcpZ, partial);
    finalize<<<FBLK, 256, 0, stream>>>(partial, counts, total, blkcnt, out);
}

// Round 4
// 659.085 us; speedup vs baseline: 1.1410x; 1.0807x over previous
//
#include <hip/hip_runtime.h>

#define BB 4096
#define CC 32000
#define CPAD 32768           // padded column count (zeros beyond CC)
#define NT 512               // threads per block
#define NI 16                // float4 chunks per thread: NT*4*NI = CPAD
#define GRID 256             // one block per CU (LDS 128 KB -> 1 block/CU)
#define RPB (BB / GRID)      // 16 rows per block
#define FBLK 128             // finalize blocks: 128*256 threads = CPAD/4 quads

typedef float v4f __attribute__((ext_vector_type(4)));

// ---- Single pass: read x once; per row exp->Z->scale, accumulate conf sums in LDS.
__global__ __launch_bounds__(NT, 2) void mdca_main(const float* __restrict__ x,
                                                   const int* __restrict__ tgt,
                                                   float* __restrict__ partial,
                                                   float* __restrict__ counts) {
    __shared__ float acc[CPAD];   // 128 KB: acc[c] = sum_r exp(x[r,c])/Z_r (block's rows)
    __shared__ float red[NT / 64];
    __shared__ float s_rcp;

    const int t = threadIdx.x;
    const int r0 = blockIdx.x * RPB;

    // zero the accumulator
    for (int i = t; i < CPAD / 4; i += NT) ((v4f*)acc)[i] = (v4f){0.f, 0.f, 0.f, 0.f};

    v4f cur[NI], nxt[NI];

    // preload row r0 into registers (thread t owns cols i*2048 + 4t .. +3)
    {
        const float* rp = x + (size_t)r0 * CC;
#pragma unroll
        for (int i = 0; i < NI; ++i) {
            const int col = i * 2048 + 4 * t;
            if (col < CC) cur[i] = __builtin_nontemporal_load((const v4f*)(rp + col));
        }
    }
    __syncthreads();  // acc zeros visible

    for (int r = 0; r < RPB; ++r) {
        // issue next row's loads FIRST so HBM stays busy through the barriers
        if (r + 1 < RPB) {
            const float* rp = x + (size_t)(r0 + r + 1) * CC;
#pragma unroll
            for (int i = 0; i < NI; ++i) {
                const int col = i * 2048 + 4 * t;
                if (col < CC) nxt[i] = __builtin_nontemporal_load((const v4f*)(rp + col));
            }
        }
        // exp current row in-register; partial sum
        float s = 0.f;
#pragma unroll
        for (int i = 0; i < NI; ++i) {
            const int col = i * 2048 + 4 * t;
            if (col < CC) {
                v4f e;
                e.x = __expf(cur[i].x); e.y = __expf(cur[i].y);
                e.z = __expf(cur[i].z); e.w = __expf(cur[i].w);
                cur[i] = e;
                s += e.x + e.y + e.z + e.w;
            }
        }
        // block reduce -> rcpZ
        for (int off = 32; off > 0; off >>= 1) s += __shfl_down(s, off);
        if ((t & 63) == 0) red[t >> 6] = s;
        __syncthreads();
        if (t == 0) {
            float z = 0.f;
#pragma unroll
            for (int w = 0; w < NT / 64; ++w) z += red[w];
            s_rcp = 1.0f / z;
        }
        __syncthreads();
        const float rz = s_rcp;
        // scale-accumulate into LDS (each thread owns its acc slots -> no races,
        // contiguous 16B per lane -> conflict-free ds_read/write_b128)
#pragma unroll
        for (int i = 0; i < NI; ++i) {
            const int col = i * 2048 + 4 * t;
            if (col < CC) {
                v4f a = ((v4f*)acc)[i * 512 + t];
                a.x += cur[i].x * rz; a.y += cur[i].y * rz;
                a.z += cur[i].z * rz; a.w += cur[i].w * rz;
                ((v4f*)acc)[i * 512 + t] = a;
            }
        }
        // rotate register buffers
        if (r + 1 < RPB) {
#pragma unroll
            for (int i = 0; i < NI; ++i) cur[i] = nxt[i];
        }
        // no barrier needed here: acc slots are thread-private; red/s_rcp reuse is
        // ordered by the two barriers above (writers of red(r+1) passed bar2(r),
        // which is after all red(r) reads; s_rcp(r+1) write is after bar1(r+1)).
    }

    // write this block's column partials (thread-private slots; no barrier needed)
    v4f* pp = (v4f*)(partial + (size_t)blockIdx.x * CPAD);
#pragma unroll
    for (int i = 0; i < NI; ++i) {
        const int col = i * 2048 + 4 * t;
        v4f a = (col < CC) ? ((v4f*)acc)[i * 512 + t] : (v4f){0.f, 0.f, 0.f, 0.f};
        pp[i * 512 + t] = a;
    }
    // fused bincount: one atomic per row
    if (t < RPB) atomicAdd(&counts[tgt[r0 + t]], 1.0f);
}

// ---- Finalize: loss = (1/(B*C)) * sum_c | sum_b partial[b][c] - counts[c] |
__global__ __launch_bounds__(256) void finalize(const float* __restrict__ partial,
                                                const float* __restrict__ counts,
                                                float* __restrict__ total,
                                                unsigned* __restrict__ blkcnt,
                                                float* __restrict__ out) {
    const int g = blockIdx.x * 256 + threadIdx.x;  // quad index, < CPAD/4
    v4f s = {0.f, 0.f, 0.f, 0.f};
    const v4f* pv = (const v4f*)partial;
    for (int b = 0; b < GRID; ++b) {
        v4f p = pv[(size_t)b * (CPAD / 4) + g];
        s.x += p.x; s.y += p.y; s.z += p.z; s.w += p.w;
    }
    float v = 0.f;
    const int c = 4 * g;
    if (c < CC) {  // c+3 < CC too (CC % 4 == 0); padded quads contribute 0
        v4f cnt = *(const v4f*)(counts + c);
        v = fabsf(s.x - cnt.x) + fabsf(s.y - cnt.y) + fabsf(s.z - cnt.z) + fabsf(s.w - cnt.w);
    }
    for (int off = 32; off > 0; off >>= 1) v += __shfl_down(v, off);
    __shared__ float wsum[4];
    if ((threadIdx.x & 63) == 0) wsum[threadIdx.x >> 6] = v;
    __syncthreads();
    if (threadIdx.x == 0) {
        atomicAdd(total, wsum[0] + wsum[1] + wsum[2] + wsum[3]);
        __threadfence();
        unsigned prev = atomicAdd(blkcnt, 1u);
        if (prev == FBLK - 1) {
            float tot = atomicAdd(total, 0.0f);  // device-scope read of final value
            out[0] = tot * (1.0f / ((float)BB * (float)CC));
        }
    }
}

extern "C" void kernel_launch(void* const* d_in, const int* in_sizes, int n_in,
                              void* d_out, int out_size, void* d_ws, size_t ws_size,
                              hipStream_t stream) {
    const float* x = (const float*)d_in[0];
    const int* tgt = (const int*)d_in[1];
    float* out = (float*)d_out;

    // ws layout (floats): partial[GRID*CPAD] | counts[CC] | total | blkcnt
    float* partial = (float*)d_ws;                       // 33,554,432 B
    float* counts = partial + (size_t)GRID * CPAD;
    float* total = counts + CC;
    unsigned* blkcnt = (unsigned*)(total + 1);

    (void)hipMemsetAsync(counts, 0, (size_t)(CC + 2) * 4, stream);

    mdca_main<<<GRID, NT, 0, stream>>>(x, tgt, partial, counts);
    finalize<<<FBLK, 256, 0, stream>>>(partial, counts, total, blkcnt, out);
}